// Round 6
// baseline (54.460 us; speedup 1.0000x reference)
//
#include <hip/hip_runtime.h>

#define N_P 256
#define N_T 32
#define OFFDIAG 65280   // 256*255
#define QROWS 1024      // 32*32
#define TAILBLKS 255    // 255*256 = 65280

// Exact reference fp order: inter / ((area_a + area_b) - inter)
__device__ __forceinline__ float iou_one(float a0, float a1, float a2, float a3,
                                         float ta,
                                         float b0, float b1, float b2, float b3,
                                         float areaB) {
    float lt0 = fmaxf(a0, b0), lt1 = fmaxf(a1, b1);
    float rb0 = fminf(a2, b2), rb1 = fminf(a3, b3);
    float w = fmaxf((rb0 - lt0) + 1.0f, 0.0f);
    float h = fmaxf((rb1 - lt1) + 1.0f, 0.0f);
    float inter = w * h;
    return inter / ((ta + areaB) - inter);
}

// ---------------------------------------------------------------------------
// Single dispatch, zero inter-block dependencies.
//  blocks [0, QROWS): one quality row each — R5's proven fat-block structure,
//    with the iou-row staging computed inline (2 IoUs/thread) instead of
//    read from a k1-produced matrix. Wave owns i-segments: rp[i] wave-uniform
//    (SGPR), rq[j] stride-1 LDS (conflict-free), 64-contiguous dword stores.
//  blocks [QROWS, QROWS+TAILBLKS): tail — per-thread best (max + first-
//    occurrence argmax over 32 targets, strict >), matched/labels/pairs.
// ---------------------------------------------------------------------------
__global__ void relpn_kernel(const float* __restrict__ pb,
                             const float* __restrict__ tb,
                             const int* __restrict__ tpl,
                             float* __restrict__ out) {
    int tid = threadIdx.x;
    unsigned blk = blockIdx.x;
    __shared__ float rp[N_P], rq[N_P];

    if (blk < QROWS) {
        // ---------------- quality row ----------------
        int pq = (int)blk;
        int p = pq >> 5, q = pq & 31;

        // uniform scalar target-box loads (SGPR)
        float pa0 = tb[p * 4 + 0], pa1 = tb[p * 4 + 1];
        float pa2 = tb[p * 4 + 2], pa3 = tb[p * 4 + 3];
        float pta = ((pa2 - pa0) + 1.0f) * ((pa3 - pa1) + 1.0f);
        float qa0 = tb[q * 4 + 0], qa1 = tb[q * 4 + 1];
        float qa2 = tb[q * 4 + 2], qa3 = tb[q * 4 + 3];
        float qta = ((qa2 - qa0) + 1.0f) * ((qa3 - qa1) + 1.0f);

        float4 B = reinterpret_cast<const float4*>(pb)[tid];
        float areaB = ((B.z - B.x) + 1.0f) * ((B.w - B.y) + 1.0f);
        // prefold 0.5 (exact scaling, commutes with rounding)
        rp[tid] = 0.5f * iou_one(pa0, pa1, pa2, pa3, pta, B.x, B.y, B.z, B.w, areaB);
        rq[tid] = 0.5f * iou_one(qa0, qa1, qa2, qa3, qta, B.x, B.y, B.z, B.w, areaB);
        __syncthreads();

        int wave = tid >> 6, lane = tid & 63;
        float* dst = out + (size_t)pq * OFFDIAG;

        for (int i0 = wave; i0 < N_P; i0 += 4) {
            int i = __builtin_amdgcn_readfirstlane(i0);   // wave-uniform -> SGPR
            float a = rp[i];                              // LDS broadcast
            int ibase = i * 255;
            #pragma unroll
            for (int m = 0; m < 4; ++m) {
                int pos = m * 64 + lane;
                if (pos < 255) {                          // only lane 63 @ m==3 masks
                    int j = pos + (pos >= i ? 1 : 0);
                    dst[ibase + pos] = a + rq[j];
                }
            }
        }
    } else {
        // ---------------- tail ----------------
        int k = (int)(blk - QROWS) * 256 + tid;           // [0, 65280)
        float* matched = out + (size_t)QROWS * OFFDIAG;
        float* labels  = matched + OFFDIAG;
        float* pbp     = labels + OFFDIAG;
        float* pip     = pbp + (size_t)OFFDIAG * 8;
        float* tbp     = pip + (size_t)OFFDIAG * 2;

        int i = (unsigned)k / 255u;
        int r = k - i * 255;
        int j = r + (r >= i ? 1 : 0);

        float4 Bi = reinterpret_cast<const float4*>(pb)[i];
        float4 Bj = reinterpret_cast<const float4*>(pb)[j];
        float areaBi = ((Bi.z - Bi.x) + 1.0f) * ((Bi.w - Bi.y) + 1.0f);
        float areaBj = ((Bj.z - Bj.x) + 1.0f) * ((Bj.w - Bj.y) + 1.0f);

        float bvi = -1.0f, bvj = -1.0f;
        int bii = 0, bij = 0;
        #pragma unroll
        for (int t = 0; t < N_T; ++t) {
            // uniform scalar loads of target box t (SGPR broadcast)
            float a0 = tb[t * 4 + 0], a1 = tb[t * 4 + 1];
            float a2 = tb[t * 4 + 2], a3 = tb[t * 4 + 3];
            float ta = ((a2 - a0) + 1.0f) * ((a3 - a1) + 1.0f);
            float vi = iou_one(a0, a1, a2, a3, ta, Bi.x, Bi.y, Bi.z, Bi.w, areaBi);
            float vj = iou_one(a0, a1, a2, a3, ta, Bj.x, Bj.y, Bj.z, Bj.w, areaBj);
            if (vi > bvi) { bvi = vi; bii = t; }          // strict > == first occurrence
            if (vj > bvj) { bvj = vj; bij = t; }
        }

        float mv = 0.5f * (bvi + bvj);
        int mi, lab;
        if (mv < 0.3f)      { mi = -1; lab = 0; }
        else if (mv < 0.5f) { mi = -2; lab = -1; }
        else                { mi = bii * N_T + bij; lab = tpl[mi]; }

        matched[k] = (float)mi;
        labels[k]  = (float)lab;

        reinterpret_cast<float4*>(pbp)[k * 2 + 0] = Bi;
        reinterpret_cast<float4*>(pbp)[k * 2 + 1] = Bj;
        pip[k * 2 + 0] = (float)i;
        pip[k * 2 + 1] = (float)j;

        if (k < QROWS) {
            int pp = k >> 5, qq = k & 31;
            reinterpret_cast<float4*>(tbp)[k * 2 + 0] =
                reinterpret_cast<const float4*>(tb)[pp];
            reinterpret_cast<float4*>(tbp)[k * 2 + 1] =
                reinterpret_cast<const float4*>(tb)[qq];
        }
    }
}

extern "C" void kernel_launch(void* const* d_in, const int* in_sizes, int n_in,
                              void* d_out, int out_size, void* d_ws, size_t ws_size,
                              hipStream_t stream) {
    const float* pb  = (const float*)d_in[0];   // proposal_boxes [256,4]
    const float* tb  = (const float*)d_in[1];   // target_boxes   [32,4]
    const int*   tpl = (const int*)d_in[2];     // target_pair_labels [1024]
    float* out = (float*)d_out;

    relpn_kernel<<<QROWS + TAILBLKS, 256, 0, stream>>>(pb, tb, tpl, out);
}

// Round 7
// 51.364 us; speedup vs baseline: 1.0603x; 1.0603x over previous
//
#include <hip/hip_runtime.h>

#define N_P 256
#define N_T 32
#define OFFDIAG 65280   // 256*255
#define QROWS 1024      // 32*32
#define TAILBLKS 255    // 255*256 = 65280

// Exact reference fp order: inter / ((area_a + area_b) - inter)
__device__ __forceinline__ float iou_one(float a0, float a1, float a2, float a3,
                                         float ta,
                                         float b0, float b1, float b2, float b3,
                                         float areaB) {
    float lt0 = fmaxf(a0, b0), lt1 = fmaxf(a1, b1);
    float rb0 = fminf(a2, b2), rb1 = fminf(a3, b3);
    float w = fmaxf((rb0 - lt0) + 1.0f, 0.0f);
    float h = fmaxf((rb1 - lt1) + 1.0f, 0.0f);
    float inter = w * h;
    return inter / ((ta + areaB) - inter);
}

// ---------------------------------------------------------------------------
// Single dispatch, zero inter-block dependencies. TAIL BLOCKS FIRST (low
// block IDs dispatch first -> tail's ~4µs hides under quality's store drain).
//  blocks [0, TAILBLKS): tail — per-thread best (max + first-occurrence
//    argmax over 32 targets, strict >), matched/labels/box+idx pairs.
//  blocks [TAILBLKS, TAILBLKS+QROWS): one quality row each — R5's proven
//    structure: inline IoU staging (2 IoUs/thread, 0.5 prefolded), wave owns
//    i-segments, rp[i] wave-uniform (SGPR), rq[j] stride-1 LDS, 64-contiguous
//    dword stores.
// ---------------------------------------------------------------------------
__global__ void relpn_kernel(const float* __restrict__ pb,
                             const float* __restrict__ tb,
                             const int* __restrict__ tpl,
                             float* __restrict__ out) {
    int tid = threadIdx.x;
    unsigned blk = blockIdx.x;
    __shared__ float rp[N_P], rq[N_P];

    if (blk >= TAILBLKS) {
        // ---------------- quality row ----------------
        int pq = (int)(blk - TAILBLKS);
        int p = pq >> 5, q = pq & 31;

        // uniform scalar target-box loads (SGPR)
        float pa0 = tb[p * 4 + 0], pa1 = tb[p * 4 + 1];
        float pa2 = tb[p * 4 + 2], pa3 = tb[p * 4 + 3];
        float pta = ((pa2 - pa0) + 1.0f) * ((pa3 - pa1) + 1.0f);
        float qa0 = tb[q * 4 + 0], qa1 = tb[q * 4 + 1];
        float qa2 = tb[q * 4 + 2], qa3 = tb[q * 4 + 3];
        float qta = ((qa2 - qa0) + 1.0f) * ((qa3 - qa1) + 1.0f);

        float4 B = reinterpret_cast<const float4*>(pb)[tid];
        float areaB = ((B.z - B.x) + 1.0f) * ((B.w - B.y) + 1.0f);
        // prefold 0.5 (exact scaling, commutes with rounding)
        rp[tid] = 0.5f * iou_one(pa0, pa1, pa2, pa3, pta, B.x, B.y, B.z, B.w, areaB);
        rq[tid] = 0.5f * iou_one(qa0, qa1, qa2, qa3, qta, B.x, B.y, B.z, B.w, areaB);
        __syncthreads();

        int wave = tid >> 6, lane = tid & 63;
        float* dst = out + (size_t)pq * OFFDIAG;

        for (int i0 = wave; i0 < N_P; i0 += 4) {
            int i = __builtin_amdgcn_readfirstlane(i0);   // wave-uniform -> SGPR
            float a = rp[i];                              // LDS broadcast
            int ibase = i * 255;
            #pragma unroll
            for (int m = 0; m < 4; ++m) {
                int pos = m * 64 + lane;
                if (pos < 255) {                          // only lane 63 @ m==3 masks
                    int j = pos + (pos >= i ? 1 : 0);
                    dst[ibase + pos] = a + rq[j];
                }
            }
        }
    } else {
        // ---------------- tail ----------------
        int k = (int)blk * 256 + tid;                     // [0, 65280)
        float* matched = out + (size_t)QROWS * OFFDIAG;
        float* labels  = matched + OFFDIAG;
        float* pbp     = labels + OFFDIAG;
        float* pip     = pbp + (size_t)OFFDIAG * 8;
        float* tbp     = pip + (size_t)OFFDIAG * 2;

        int i = (unsigned)k / 255u;
        int r = k - i * 255;
        int j = r + (r >= i ? 1 : 0);

        float4 Bi = reinterpret_cast<const float4*>(pb)[i];
        float4 Bj = reinterpret_cast<const float4*>(pb)[j];
        float areaBi = ((Bi.z - Bi.x) + 1.0f) * ((Bi.w - Bi.y) + 1.0f);
        float areaBj = ((Bj.z - Bj.x) + 1.0f) * ((Bj.w - Bj.y) + 1.0f);

        float bvi = -1.0f, bvj = -1.0f;
        int bii = 0, bij = 0;
        #pragma unroll
        for (int t = 0; t < N_T; ++t) {
            // uniform scalar loads of target box t (SGPR broadcast)
            float a0 = tb[t * 4 + 0], a1 = tb[t * 4 + 1];
            float a2 = tb[t * 4 + 2], a3 = tb[t * 4 + 3];
            float ta = ((a2 - a0) + 1.0f) * ((a3 - a1) + 1.0f);
            float vi = iou_one(a0, a1, a2, a3, ta, Bi.x, Bi.y, Bi.z, Bi.w, areaBi);
            float vj = iou_one(a0, a1, a2, a3, ta, Bj.x, Bj.y, Bj.z, Bj.w, areaBj);
            if (vi > bvi) { bvi = vi; bii = t; }          // strict > == first occurrence
            if (vj > bvj) { bvj = vj; bij = t; }
        }

        float mv = 0.5f * (bvi + bvj);
        int mi, lab;
        if (mv < 0.3f)      { mi = -1; lab = 0; }
        else if (mv < 0.5f) { mi = -2; lab = -1; }
        else                { mi = bii * N_T + bij; lab = tpl[mi]; }

        matched[k] = (float)mi;
        labels[k]  = (float)lab;

        reinterpret_cast<float4*>(pbp)[k * 2 + 0] = Bi;
        reinterpret_cast<float4*>(pbp)[k * 2 + 1] = Bj;
        pip[k * 2 + 0] = (float)i;
        pip[k * 2 + 1] = (float)j;

        if (k < QROWS) {
            int pp = k >> 5, qq = k & 31;
            reinterpret_cast<float4*>(tbp)[k * 2 + 0] =
                reinterpret_cast<const float4*>(tb)[pp];
            reinterpret_cast<float4*>(tbp)[k * 2 + 1] =
                reinterpret_cast<const float4*>(tb)[qq];
        }
    }
}

extern "C" void kernel_launch(void* const* d_in, const int* in_sizes, int n_in,
                              void* d_out, int out_size, void* d_ws, size_t ws_size,
                              hipStream_t stream) {
    const float* pb  = (const float*)d_in[0];   // proposal_boxes [256,4]
    const float* tb  = (const float*)d_in[1];   // target_boxes   [32,4]
    const int*   tpl = (const int*)d_in[2];     // target_pair_labels [1024]
    float* out = (float*)d_out;

    relpn_kernel<<<TAILBLKS + QROWS, 256, 0, stream>>>(pb, tb, tpl, out);
}